// Round 10
// baseline (125.768 us; speedup 1.0000x reference)
//
#include <hip/hip_runtime.h>
#include <hip/hip_bf16.h>

// GraphAttentionLayer: out = elu( softmax_row( where(adj>0, lrelu(src_i+dst_j), 0) ) @ wh )
//
// R9 post-mortem: depth-3 prefetch + 16 waves/CU changed nothing -> NOT latency.
// Surviving theory: scattered vmem geometry (16 rows x 32KB stride / instr) caps
// the request path; contiguous access (fills, R8) is 2.4-7x faster.
// R10: split adj streaming out of k2 entirely.
//   k0_pack: adj -> 1-bit mask (8MB). One row per wave, 1KB contiguous per
//            instruction, 32KB sequential per wave — m13-class pattern.
//   k2: NO vector-memory in the loop. Masks via wave-uniform s_load (K$);
//       B LDS-resident (R7 staging, one barrier); P via wave-private LDS;
//       row-sums via 5th MFMA with constant ones-column B fragment.
// Mask layout: per 256-col group g of row r: 4 u64 at maskb[(r*32+g)*4+s];
//   bit l of u64 s = (adj[r][g*256 + 4*l + s] > 0).

constexpr int N_ROWS = 8192;
constexpr int F_IN   = 128;
constexpr int F_OUT  = 64;
#define LRELU_A 0.2f
#define LOG2E   1.4426950408889634f

// workspace layout (bytes)
constexpr size_t OFF_WHT  = 0;                     // 1 MiB bf16 [f][row]
constexpr size_t OFF_SRC  = 1048576;               // 8192 f32 (x log2e)
constexpr size_t OFF_DST  = OFF_SRC + 32768;       // 8192 f32 (x log2e)
constexpr size_t OFF_LP   = OFF_DST + 32768;       // S*8192 f32
constexpr size_t OFF_ACC  = OFF_LP + 16 * 32768;   // 16*8192*64 f32 = 32 MiB
constexpr size_t OFF_MASK = OFF_ACC + 33554432;    // 8192 rows x 1 KiB = 8 MiB

typedef __attribute__((ext_vector_type(4))) float f32x4;
typedef __attribute__((ext_vector_type(2))) float f32x2;
typedef __attribute__((ext_vector_type(4))) int   i32x4;
typedef __attribute__((ext_vector_type(8))) short s16x8;
typedef __attribute__((ext_vector_type(2))) unsigned long long u64x2;

static __device__ __forceinline__ short f2bf(float f) {
  unsigned u = __float_as_uint(f);
  u = (u + 0x7fffu + ((u >> 16) & 1u)) >> 16;  // RNE
  return (short)u;
}

// ---------------- Kernel 0: adj -> bitmask (THE adj stream, contiguous) -----
// 8192 waves; wave w packs row w: 32 iters x 1KB contiguous reads.
__global__ __launch_bounds__(256) void k0_pack(
    const int* __restrict__ adj, unsigned long long* __restrict__ maskb)
{
  const int lane = threadIdx.x & 63;
  const int w    = blockIdx.x * 4 + (threadIdx.x >> 6);   // row index
  const int* base = adj + (size_t)w * N_ROWS + lane * 4;

  i32x4 cur = __builtin_nontemporal_load((const i32x4*)(base));
#pragma unroll
  for (int it = 0; it < 32; ++it) {
    i32x4 nxt;
    if (it + 1 < 32)
      nxt = __builtin_nontemporal_load((const i32x4*)(base + (it + 1) * 256));
    const unsigned long long b0 = __ballot(cur.x > 0);
    const unsigned long long b1 = __ballot(cur.y > 0);
    const unsigned long long b2 = __ballot(cur.z > 0);
    const unsigned long long b3 = __ballot(cur.w > 0);
    if (lane < 4) {
      const unsigned long long v = lane == 0 ? b0 : lane == 1 ? b1
                                 : lane == 2 ? b2 : b3;
      maskb[((size_t)w * 32 + it) * 4 + lane] = v;   // 32B contiguous
    }
    cur = nxt;
  }
}

// ---------------- Kernel 1: wh = x@w ; src/dst (x log2e) ; whT (bf16) -------
__global__ __launch_bounds__(256) void k1_proj(
    const float* __restrict__ x, const float* __restrict__ w,
    const float* __restrict__ a, short* __restrict__ whT,
    float* __restrict__ src, float* __restrict__ dst)
{
  const int lane = threadIdx.x & 63;   // = output feature f
  const int wid  = threadIdx.x >> 6;
  const int rowBase = blockIdx.x * 32 + wid * 8;

  float acc[8];
#pragma unroll
  for (int r = 0; r < 8; ++r) acc[r] = 0.0f;

#pragma unroll 1
  for (int kc = 0; kc < 4; ++kc) {
    float wreg[32];
#pragma unroll
    for (int kk = 0; kk < 32; ++kk)
      wreg[kk] = w[(kc * 32 + kk) * F_OUT + lane];
#pragma unroll
    for (int r = 0; r < 8; ++r) {
      const f32x4* xp = (const f32x4*)(x + (size_t)(rowBase + r) * F_IN + kc * 32);
#pragma unroll
      for (int q = 0; q < 8; ++q) {
        f32x4 xv = xp[q];
        acc[r] = fmaf(xv.x, wreg[4*q+0], acc[r]);
        acc[r] = fmaf(xv.y, wreg[4*q+1], acc[r]);
        acc[r] = fmaf(xv.z, wreg[4*q+2], acc[r]);
        acc[r] = fmaf(xv.w, wreg[4*q+3], acc[r]);
      }
    }
  }

  s16x8 hb;
#pragma unroll
  for (int r = 0; r < 8; ++r) hb[r] = f2bf(acc[r]);
  *(s16x8*)&whT[(size_t)lane * N_ROWS + rowBase] = hb;

  const float aS = a[lane];
  const float aD = a[F_OUT + lane];
#pragma unroll
  for (int r = 0; r < 8; ++r) {
    float ts = acc[r] * aS;
    float td = acc[r] * aD;
#pragma unroll
    for (int off = 32; off > 0; off >>= 1) {
      ts += __shfl_xor(ts, off, 64);
      td += __shfl_xor(td, off, 64);
    }
    if (lane == 0) {
      src[rowBase + r] = ts * LOG2E;
      dst[rowBase + r] = td * LOG2E;
    }
  }
}

// ---------------- Kernel 2: mask-driven fused exp+PV (no loop vmem) ---------
// grid: (N/128, 16) x 512 thr (8 waves x 16 rows). LDS: B 64KB + P 8x4KB.
template<int S>
__global__ __launch_bounds__(512, 2) void k2_attn(
    const unsigned long long* __restrict__ maskb, const short* __restrict__ whT,
    const float* __restrict__ src, const float* __restrict__ dst,
    float* __restrict__ acc_part, float* __restrict__ l_part)
{
  constexpr int JLEN = N_ROWS / S;    // 512
  __shared__ short Blds[64 * JLEN];   // 64KB, byte ^= (f&7)<<4
  __shared__ short Plds[8][16 * 128]; // 8 x 4KB wave-private, ^= (r&7)<<4

  const int tid  = threadIdx.x;
  const int lane = tid & 63;
  const int wid  = tid >> 6;
  const int s    = blockIdx.y;
  const int jbase = s * JLEN;
  const int jg0   = jbase / 256;      // first 256-col group
  const int rowg  = blockIdx.x * 128 + wid * 16;
  const int r16   = lane & 15;
  const int kq    = lane >> 4;

  // ---- stage B slice (swizzled); ONE barrier in the whole kernel ----
#pragma unroll
  for (int q = 0; q < 8; ++q) {
    const int m   = tid + q * 512;
    const int f   = m >> 6;
    const int c16 = m & 63;
    const s16x8 v = *(const s16x8*)(whT + (size_t)f * N_ROWS + jbase + c16 * 8);
    *(s16x8*)((char*)Blds + f * (JLEN * 2) + ((c16 * 16) ^ ((f & 7) << 4))) = v;
  }
  __syncthreads();

  // preloads (all loop inputs -> registers/SGPRs)
  f32x2 dstv[4];
#pragma unroll
  for (int c = 0; c < 4; ++c)
    dstv[c] = *(const f32x2*)(dst + jbase + c * 128 + lane * 2);
  const int shiftLo = lane >> 1;          // bit index within dword
  const bool lodd = lane & 1;
  s16x8 bones;
#pragma unroll
  for (int j = 0; j < 8; ++j) bones[j] = (short)((r16 == 0) ? 0x3F80 : 0);

  f32x4 acc0 = {0,0,0,0}, acc1 = {0,0,0,0}, acc2 = {0,0,0,0}, acc3 = {0,0,0,0};
  f32x4 accl = {0,0,0,0};   // row-sums via ones-column MFMA
  short* const myP = &Plds[wid][0];

#pragma unroll
  for (int c = 0; c < 4; ++c) {
    const int gofs = (jg0 + (c >> 1)) * 4;      // u64 index of group in row
    const int shA  = (c & 1) * 32 + shiftLo;    // 64-bit shift amount
    // ---- phase A: 16 rows, 2 cols/lane, mask via s_load ----
#pragma unroll
    for (int r = 0; r < 16; ++r) {
      const float sv = src[rowg + r];           // uniform -> scalar load
      const u64x2* mp = (const u64x2*)(maskb + (size_t)(rowg + r) * 128 + gofs);
      const u64x2 mlo = mp[0];                  // m0, m1
      const u64x2 mhi = mp[1];                  // m2, m3
      const unsigned long long mSelA = lodd ? mhi.x : mlo.x;  // s=2(l&1)
      const unsigned long long mSelB = lodd ? mhi.y : mlo.y;  // s=2(l&1)+1
      const bool bA = (mSelA >> shA) & 1;
      const bool bB = (mSelB >> shA) & 1;
      float e0 = sv + dstv[c].x; e0 = fmaxf(e0, LRELU_A * e0);
      float e1 = sv + dstv[c].y; e1 = fmaxf(e1, LRELU_A * e1);
      const float p0 = bA ? __builtin_amdgcn_exp2f(e0) : 1.0f;
      const float p1 = bB ? __builtin_amdgcn_exp2f(e1) : 1.0f;
      union { unsigned u; __hip_bfloat16 b[2]; } pk;
      pk.b[0] = __float2bfloat16(p0); pk.b[1] = __float2bfloat16(p1);
      *(unsigned*)((char*)myP + r * 256 + ((lane * 4) ^ ((r & 7) << 4))) = pk.u;
    }
    // ---- phase B: MFMA from wave-private P + block B (in-order DS => safe) --
#pragma unroll
    for (int kcc = 0; kcc < 4; ++kcc) {
      const s16x8 af = *(const s16x8*)((char*)myP + r16 * 256
                        + ((kcc * 64 + kq * 16) ^ ((r16 & 7) << 4)));
      const int colb = (c * 128 + kcc * 32 + kq * 8) * 2;
#define BLD(ft) (*(const s16x8*)((char*)Blds + ((ft) * 16 + r16) * (JLEN * 2) \
                  + (colb ^ ((((ft) * 16 + r16) & 7) << 4))))
      acc0 = __builtin_amdgcn_mfma_f32_16x16x32_bf16(af, BLD(0), acc0, 0, 0, 0);
      acc1 = __builtin_amdgcn_mfma_f32_16x16x32_bf16(af, BLD(1), acc1, 0, 0, 0);
      acc2 = __builtin_amdgcn_mfma_f32_16x16x32_bf16(af, BLD(2), acc2, 0, 0, 0);
      acc3 = __builtin_amdgcn_mfma_f32_16x16x32_bf16(af, BLD(3), acc3, 0, 0, 0);
      accl = __builtin_amdgcn_mfma_f32_16x16x32_bf16(af, bones, accl, 0, 0, 0);
#undef BLD
    }
  }

  // ---- epilogue ----
  // C/D: col = lane&15, row = (lane>>4)*4 + reg
  if (r16 == 0) {
#pragma unroll
    for (int rg = 0; rg < 4; ++rg)
      l_part[(size_t)s * N_ROWS + rowg + kq * 4 + rg] = accl[rg];
  }
#define STORE_ACC(av, nt) _Pragma("unroll") \
  for (int rg = 0; rg < 4; ++rg) { \
    const int row = rowg + kq * 4 + rg; \
    __builtin_nontemporal_store((av)[rg], \
        acc_part + ((size_t)s * N_ROWS + row) * F_OUT + (nt) * 16 + r16); \
  }
  STORE_ACC(acc0, 0) STORE_ACC(acc1, 1) STORE_ACC(acc2, 2) STORE_ACC(acc3, 3)
#undef STORE_ACC
}

// ---------------- Kernel 3: combine partials, normalize, ELU ----------------
template<int S>
__global__ __launch_bounds__(256) void k3_combine(
    const float* __restrict__ acc_part, const float* __restrict__ l_part,
    float* __restrict__ out)
{
  const int idx = blockIdx.x * 256 + threadIdx.x;
  const int row = idx >> 4;
  const int f4  = idx & 15;
  f32x4 h = {0.f, 0.f, 0.f, 0.f};
  float l = 0.f;
#pragma unroll
  for (int s = 0; s < S; ++s) {
    h += *(const f32x4*)(acc_part + ((size_t)s * N_ROWS + row) * F_OUT + 4 * f4);
    l += l_part[(size_t)s * N_ROWS + row];
  }
  const float inv = 1.0f / l;
  f32x4 o;
  {
    float v0 = h.x * inv; o.x = v0 > 0.f ? v0 : (__expf(v0) - 1.0f);
    float v1 = h.y * inv; o.y = v1 > 0.f ? v1 : (__expf(v1) - 1.0f);
    float v2 = h.z * inv; o.z = v2 > 0.f ? v2 : (__expf(v2) - 1.0f);
    float v3 = h.w * inv; o.w = v3 > 0.f ? v3 : (__expf(v3) - 1.0f);
  }
  *(f32x4*)(out + (size_t)row * F_OUT + 4 * f4) = o;
}

// ---------------- launch ----------------
extern "C" void kernel_launch(void* const* d_in, const int* in_sizes, int n_in,
                              void* d_out, int out_size, void* d_ws, size_t ws_size,
                              hipStream_t stream) {
  const float* x   = (const float*)d_in[0];
  const int*   adj = (const int*)d_in[1];
  const float* w   = (const float*)d_in[2];
  const float* a   = (const float*)d_in[3];
  float* out = (float*)d_out;
  char* ws = (char*)d_ws;

  short* whT      = (short*)(ws + OFF_WHT);
  float* src      = (float*)(ws + OFF_SRC);
  float* dst      = (float*)(ws + OFF_DST);
  float* l_part   = (float*)(ws + OFF_LP);
  float* acc_part = (float*)(ws + OFF_ACC);
  unsigned long long* maskb = (unsigned long long*)(ws + OFF_MASK);

  k0_pack<<<N_ROWS / 4, 256, 0, stream>>>(adj, maskb);
  k1_proj<<<N_ROWS / 32, 256, 0, stream>>>(x, w, a, whT, src, dst);
  k2_attn<16><<<dim3(N_ROWS / 128, 16), 512, 0, stream>>>(maskb, whT, src, dst,
                                                          acc_part, l_part);
  k3_combine<16><<<(N_ROWS * F_OUT / 4) / 256, 256, 0, stream>>>(acc_part, l_part, out);
}